// Round 1
// 365.344 us; speedup vs baseline: 1.0088x; 1.0088x over previous
//
#include <hip/hip_runtime.h>
#include <math.h>

#ifndef M_PI
#define M_PI 3.14159265358979323846
#endif

constexpr int S_LEN    = 176400;
constexpr int NFFT     = 2048;
constexpr int NC       = 1024;
constexpr int HOP_     = 441;
constexpr int T_FRAMES = 401;
constexpr int F_BINS   = 1025;
constexpr int F_STRIDE = 1028;     // fp32 spec row stride (16B aligned)
constexpr int N_CH     = 64;
constexpr float EPS_   = 1e-8f;
constexpr float C1_    = 0.0004f;
constexpr float C2_    = 0.0036f;
constexpr float COV_NORM_ = 49.0f / 48.0f;

// workspace float offsets
constexpr int WIN_OFF  = 0;        // float[2048] hann window
constexpr int TWG_OFF  = 2048;     // float2[768]  tw[e] = exp(-2pi i e/1024)
constexpr int UTW_OFF  = 3584;     // float2[1025] exp(-i pi r/1024)
constexpr int SPEC_OFF = 5696;
constexpr int RPB_     = 10;
constexpr int N_CHUNKS = 40;

// LDS bank swizzle: phys(a) = a ^ ((a>>2)&15).  Bijective on [0,1024).
// For float2 (b64) accesses, every pattern used below (pack writes, stage reads
// b+256k, stage-i writes q+4*ps+j*s for s=1..256, unpack reads +/-r) yields 16
// distinct values mod 16 per 16 consecutive lanes -> conflict-free (verified
// per-pattern by the GF(2) triangular-invertibility of the low-nibble map).
// FFT1 lives at a fixed +1024-float2 (+8 KB) offset: bank pattern identical.
__device__ __forceinline__ int phys(int i) { return i ^ ((i >> 2) & 15); }

__device__ __forceinline__ float2 cadd(float2 a, float2 b){ return make_float2(a.x+b.x, a.y+b.y); }
__device__ __forceinline__ float2 csub(float2 a, float2 b){ return make_float2(a.x-b.x, a.y-b.y); }
__device__ __forceinline__ float2 cmul(float2 a, float2 b){ return make_float2(a.x*b.x-a.y*b.y, a.x*b.y+a.y*b.x); }

__global__ __launch_bounds__(256) void init_tables_kernel(float* __restrict__ ws, float* __restrict__ out) {
    const int idx = blockIdx.x * 256 + threadIdx.x;
    if (idx < 64) out[idx] = 0.0f;
    if (idx < NFFT) {
        ws[WIN_OFF + idx] = 0.5f - 0.5f * cosf((float)(2.0 * M_PI / NFFT) * (float)idx);
    }
    if (idx < 768) {
        float ang = -2.0f * (float)M_PI * (float)idx / (float)NC;
        float s, c; sincosf(ang, &s, &c);
        ws[TWG_OFF + 2*idx] = c; ws[TWG_OFF + 2*idx+1] = s;
    }
    if (idx < F_BINS) {
        float ang = -(float)M_PI * (float)idx / (float)NC;
        float s, c; sincosf(ang, &s, &c);
        ws[UTW_OFF + 2*idx] = c; ws[UTW_OFF + 2*idx+1] = s;
    }
}

// One radix-4 Stockham butterfly: read 4 from A, write 4 twiddled to B.
// Addresses/twiddles are passed in so the two FFTs of a block share them;
// the second FFT's A/B differ only by a +1024-float2 compile-time offset,
// which folds into the ds op's offset: immediate (zero extra address VALU).
__device__ __forceinline__ void r4_bfly(
    const float2* __restrict__ A, float2* __restrict__ B,
    int r0, int r1, int r2, int r3,
    int o0, int o1, int o2, int o3,
    float2 w1, float2 w2, float2 w3)
{
    float2 x0c = A[r0];
    float2 x1c = A[r1];
    float2 x2c = A[r2];
    float2 x3c = A[r3];

    float2 t0 = cadd(x0c, x2c);
    float2 t1 = csub(x0c, x2c);
    float2 t2 = cadd(x1c, x3c);
    float2 t3 = csub(x1c, x3c);

    float2 y0 = cadd(t0, t2);
    float2 y2 = csub(t0, t2);
    float2 y1 = make_float2(t1.x + t3.y, t1.y - t3.x);   // t1 - i*t3
    float2 y3 = make_float2(t1.x - t3.y, t1.y + t3.x);   // t1 + i*t3

    B[o0] = y0;
    B[o1] = cmul(y1, w1);
    B[o2] = cmul(y2, w2);
    B[o3] = cmul(y3, w3);
}

// Block-wide DUAL 1024-pt complex radix-4 Stockham: each block computes frame t
// of channel ch for BOTH input tensors (x0, x1).  The two FFTs share all
// addressing, reflect logic, window, twiddle and utw fetches -- only the
// butterfly arithmetic duplicates (the useful work).  32 KB LDS/block ->
// 5 blocks/CU (20 waves); two independent dep-chains/thread restore ILP.
__global__ __launch_bounds__(256, 5) void stft_mag_kernel(
    const float* __restrict__ x0, const float* __restrict__ x1,
    float* __restrict__ ws, int ch0, int nch, int swizzle)
{
    __shared__ float2 bufA[2 * NC];
    __shared__ float2 bufB[2 * NC];

    const int tid = threadIdx.x;

    int ch, t;
    if (swizzle) {
        int g = blockIdx.x;
        ch = ch0 + (g & 7) * 8 + ((g >> 3) & 7);
        t  = g >> 6;
    } else {
        t  = blockIdx.x;
        ch = ch0 + blockIdx.y;
    }

    const float* __restrict__ xin0 = x0 + (size_t)ch * S_LEN;
    const float* __restrict__ xin1 = x1 + (size_t)ch * S_LEN;
    const float*  __restrict__ win = ws + WIN_OFF;
    const float2* __restrict__ twg = (const float2*)(ws + TWG_OFF);
    const float2* __restrict__ utw = (const float2*)(ws + UTW_OFF);

    // ---- pack: flat float index n over [0,2048); complex ci = n>>1 (swizzled)
    const int base = t * HOP_ - NFFT / 2;
    float* fA0 = (float*)bufA;            // FFT0 halves
    float* fA1 = (float*)(bufA + NC);     // FFT1 halves (+8 KB)
    if (base >= 0 && base + NFFT <= S_LEN) {
        // interior frame (395 of 401): no reflect math
        #pragma unroll
        for (int k = 0; k < NFFT / 256; ++k) {
            int n = k * 256 + tid;
            int j = base + n;
            float w = win[n];
            int p = 2 * phys(n >> 1) + (n & 1);
            fA0[p] = xin0[j] * w;
            fA1[p] = xin1[j] * w;
        }
    } else {
        #pragma unroll
        for (int k = 0; k < NFFT / 256; ++k) {
            int n = k * 256 + tid;
            int j = base + n;
            j = (j < 0) ? -j : j;
            j = (j >= S_LEN) ? (2 * S_LEN - 2 - j) : j;
            float w = win[n];
            int p = 2 * phys(n >> 1) + (n & 1);
            fA0[p] = xin0[j] * w;
            fA1[p] = xin1[j] * w;
        }
    }
    __syncthreads();

    // ---- 5-stage radix-4 Stockham DIF (R2-verified butterfly/twiddles), x2 FFTs
    float2* A = bufA;
    float2* B = bufB;
    #pragma unroll
    for (int i = 0; i < 5; ++i) {
        const int s_ = 1 << (2 * i);
        const int q  = tid & (s_ - 1);
        const int ps = tid - q;            // p * s

        const int r0 = phys(tid);
        const int r1 = phys(tid + 256);
        const int r2 = phys(tid + 512);
        const int r3 = phys(tid + 768);

        const float2 w1 = twg[ps];
        const float2 w2 = twg[2 * ps];
        const float2 w3 = twg[3 * ps];

        const int o  = q + 4 * ps;
        const int o0 = phys(o);
        const int o1 = phys(o + s_);
        const int o2 = phys(o + 2 * s_);
        const int o3 = phys(o + 3 * s_);

        r4_bfly(A,      B,      r0, r1, r2, r3, o0, o1, o2, o3, w1, w2, w3);
        r4_bfly(A + NC, B + NC, r0, r1, r2, r3, o0, o1, o2, o3, w1, w2, w3);

        __syncthreads();
        float2* tmp = A; A = B; B = tmp;
    }

    // ---- real-FFT unpack + magnitude + fp32 coalesced stores (both tensors)
    const size_t perT = (size_t)T_FRAMES * F_STRIDE;
    float* __restrict__ sout0 =
        ws + SPEC_OFF + (size_t)(ch - ch0) * perT + (size_t)t * F_STRIDE;
    float* __restrict__ sout1 = sout0 + (size_t)nch * perT;
    #pragma unroll
    for (int k = 0; k < 5; ++k) {
        int r = k * 256 + tid;
        if (k < 4 || tid == 0) {
            const int ra = phys(r & (NC - 1));
            const int rb = phys((NC - r) & (NC - 1));
            float2 wu = utw[r];

            {   // tensor 0
                float2 Zr = A[ra];
                float2 Zn = A[rb];
                float Ex = 0.5f * (Zr.x + Zn.x);
                float Ey = 0.5f * (Zr.y - Zn.y);
                float Ox = 0.5f * (Zr.y + Zn.y);
                float Oy = 0.5f * (Zn.x - Zr.x);
                float Xx = Ex + wu.x * Ox - wu.y * Oy;
                float Xy = Ey + wu.x * Oy + wu.y * Ox;
                sout0[r] = sqrtf(fmaxf(Xx * Xx + Xy * Xy, EPS_));
            }
            {   // tensor 1
                float2 Zr = A[NC + ra];
                float2 Zn = A[NC + rb];
                float Ex = 0.5f * (Zr.x + Zn.x);
                float Ey = 0.5f * (Zr.y - Zn.y);
                float Ox = 0.5f * (Zr.y + Zn.y);
                float Oy = 0.5f * (Zn.x - Zr.x);
                float Xx = Ex + wu.x * Ox - wu.y * Oy;
                float Xy = Ey + wu.x * Oy + wu.y * Ox;
                sout1[r] = sqrtf(fmaxf(Xx * Xx + Xy * Xy, EPS_));
            }
        }
    }
}

// SSIM (proven R5/R7): thread owns 4 cols; float4 global loads; rolling vertical
// sums; 5 scalar LDS arrays with lane stride 5 -> conflict-free.
__global__ __launch_bounds__(256) void ssim_kernel(
    const float* __restrict__ ws, float* __restrict__ out,
    int ch0, int nch)
{
    __shared__ float csx[1284], csy[1284], csxx[1284], csyy[1284], csxy[1284];
    __shared__ double red[256];

    const int tid = threadIdx.x;
    const int cg  = blockIdx.y;
    const int ch  = ch0 + cg;
    const float* __restrict__ spec = ws + SPEC_OFF;
    const size_t per_ch = (size_t)T_FRAMES * F_STRIDE;
    const float* __restrict__ X = spec + (size_t)cg * per_ch;
    const float* __restrict__ Y = spec + ((size_t)nch + cg) * per_ch;

    const int t_begin = 3 + blockIdx.x * RPB_;
    const int t_end_  = min(t_begin + RPB_, T_FRAMES - 3);

    const int fv = tid << 2;
    const bool last = (tid == 255);
    const float inv49 = 1.0f / 49.0f;
    double acc = 0.0;

    float sx[4] = {0,0,0,0}, sy[4] = {0,0,0,0}, sxx[4] = {0,0,0,0},
          syy[4] = {0,0,0,0}, sxy[4] = {0,0,0,0};
    float s5[5] = {0,0,0,0,0};

    for (int rr = t_begin - 3; rr < t_begin + 3; ++rr) {
        float4 xv = *(const float4*)(X + (size_t)rr * F_STRIDE + fv);
        float4 yv = *(const float4*)(Y + (size_t)rr * F_STRIDE + fv);
        float xa[4] = {xv.x, xv.y, xv.z, xv.w}, ya[4] = {yv.x, yv.y, yv.z, yv.w};
        #pragma unroll
        for (int c = 0; c < 4; ++c) {
            sx[c] += xa[c]; sy[c] += ya[c];
            sxx[c] += xa[c]*xa[c]; syy[c] += ya[c]*ya[c]; sxy[c] += xa[c]*ya[c];
        }
        if (last) {
            float xe = X[(size_t)rr * F_STRIDE + 1024];
            float ye = Y[(size_t)rr * F_STRIDE + 1024];
            s5[0] += xe; s5[1] += ye; s5[2] += xe*xe; s5[3] += ye*ye; s5[4] += xe*ye;
        }
    }

    float4 ax, ay, bx, by; float a5x=0, a5y=0, b5x=0, b5y=0;
    ax = *(const float4*)(X + (size_t)(t_begin + 3) * F_STRIDE + fv);
    ay = *(const float4*)(Y + (size_t)(t_begin + 3) * F_STRIDE + fv);
    bx = *(const float4*)(X + (size_t)(t_begin - 3) * F_STRIDE + fv);
    by = *(const float4*)(Y + (size_t)(t_begin - 3) * F_STRIDE + fv);
    if (last) {
        a5x = X[(size_t)(t_begin + 3) * F_STRIDE + 1024];
        a5y = Y[(size_t)(t_begin + 3) * F_STRIDE + 1024];
        b5x = X[(size_t)(t_begin - 3) * F_STRIDE + 1024];
        b5y = Y[(size_t)(t_begin - 3) * F_STRIDE + 1024];
    }

    const int fo = 3 + (tid << 2);

    for (int t = t_begin; t < t_end_; ++t) {
        {
            float xa[4] = {ax.x, ax.y, ax.z, ax.w}, ya[4] = {ay.x, ay.y, ay.z, ay.w};
            #pragma unroll
            for (int c = 0; c < 4; ++c) {
                sx[c] += xa[c]; sy[c] += ya[c];
                sxx[c] += xa[c]*xa[c]; syy[c] += ya[c]*ya[c]; sxy[c] += xa[c]*ya[c];
                int p = 5 * tid + c;
                csx[p] = sx[c]; csy[p] = sy[c];
                csxx[p] = sxx[c]; csyy[p] = syy[c]; csxy[p] = sxy[c];
            }
            if (last) {
                s5[0] += a5x; s5[1] += a5y; s5[2] += a5x*a5x; s5[3] += a5y*a5y; s5[4] += a5x*a5y;
                csx[1280] = s5[0]; csy[1280] = s5[1];
                csxx[1280] = s5[2]; csyy[1280] = s5[3]; csxy[1280] = s5[4];
            }
        }
        __syncthreads();

        {
            float xa[4] = {bx.x, bx.y, bx.z, bx.w}, ya[4] = {by.x, by.y, by.z, by.w};
            #pragma unroll
            for (int c = 0; c < 4; ++c) {
                sx[c] -= xa[c]; sy[c] -= ya[c];
                sxx[c] -= xa[c]*xa[c]; syy[c] -= ya[c]*ya[c]; sxy[c] -= xa[c]*ya[c];
            }
            if (last) {
                s5[0] -= b5x; s5[1] -= b5y; s5[2] -= b5x*b5x; s5[3] -= b5y*b5y; s5[4] -= b5x*b5y;
            }
        }
        if (t + 1 < t_end_) {
            ax = *(const float4*)(X + (size_t)(t + 4) * F_STRIDE + fv);
            ay = *(const float4*)(Y + (size_t)(t + 4) * F_STRIDE + fv);
            bx = *(const float4*)(X + (size_t)(t - 2) * F_STRIDE + fv);
            by = *(const float4*)(Y + (size_t)(t - 2) * F_STRIDE + fv);
            if (last) {
                a5x = X[(size_t)(t + 4) * F_STRIDE + 1024];
                a5y = Y[(size_t)(t + 4) * F_STRIDE + 1024];
                b5x = X[(size_t)(t - 2) * F_STRIDE + 1024];
                b5y = Y[(size_t)(t - 2) * F_STRIDE + 1024];
            }
        }

        if (tid < 255) {
            float tx[10], ty[10], txx[10], tyy[10], txy[10];
            #pragma unroll
            for (int d = 0; d < 10; ++d) {
                int p = 5 * tid + d + (d >> 2);
                tx[d] = csx[p]; ty[d] = csy[p];
                txx[d] = csxx[p]; tyy[d] = csyy[p]; txy[d] = csxy[p];
            }
            float wx  = tx[0]+tx[1]+tx[2]+tx[3]+tx[4]+tx[5]+tx[6];
            float wy  = ty[0]+ty[1]+ty[2]+ty[3]+ty[4]+ty[5]+ty[6];
            float wxx = txx[0]+txx[1]+txx[2]+txx[3]+txx[4]+txx[5]+txx[6];
            float wyy = tyy[0]+tyy[1]+tyy[2]+tyy[3]+tyy[4]+tyy[5]+tyy[6];
            float wxy = txy[0]+txy[1]+txy[2]+txy[3]+txy[4]+txy[5]+txy[6];
            #pragma unroll
            for (int c = 0; c < 4; ++c) {
                if (fo + c <= 1021) {
                    float ux  = wx * inv49, uy  = wy * inv49;
                    float uxx = wxx * inv49, uyy = wyy * inv49, uxy = wxy * inv49;
                    float vx  = COV_NORM_ * (uxx - ux * ux);
                    float vy  = COV_NORM_ * (uyy - uy * uy);
                    float vxy = COV_NORM_ * (uxy - ux * uy);
                    float Sv = ((2.f * ux * uy + C1_) * (2.f * vxy + C2_)) /
                               ((ux * ux + uy * uy + C1_) * (vx + vy + C2_));
                    acc += (double)Sv;
                }
                if (c < 3) {
                    wx  += tx[c+7]  - tx[c];
                    wy  += ty[c+7]  - ty[c];
                    wxx += txx[c+7] - txx[c];
                    wyy += tyy[c+7] - tyy[c];
                    wxy += txy[c+7] - txy[c];
                }
            }
        }
        __syncthreads();
    }

    red[tid] = acc;
    __syncthreads();
    for (int off = 128; off > 0; off >>= 1) {
        if (tid < off) red[tid] += red[tid + off];
        __syncthreads();
    }
    if (tid == 0) {
        atomicAdd(&out[ch], (float)(red[0] / (395.0 * 1019.0)));
    }
}

extern "C" void kernel_launch(void* const* d_in, const int* in_sizes, int n_in,
                              void* d_out, int out_size, void* d_ws, size_t ws_size,
                              hipStream_t stream) {
    const float* x0 = (const float*)d_in[0];   // output
    const float* x1 = (const float*)d_in[1];   // target
    float* out = (float*)d_out;
    float* ws  = (float*)d_ws;

    const size_t table_bytes  = (size_t)SPEC_OFF * sizeof(float);
    const size_t per_ch_bytes = (size_t)2 * T_FRAMES * F_STRIDE * sizeof(float);
    int G = (int)((ws_size - table_bytes) / per_ch_bytes);
    if (G > N_CH) G = N_CH;
    if (G < 1)    G = 1;

    init_tables_kernel<<<dim3(16), dim3(256), 0, stream>>>(ws, out);

    for (int ch0 = 0; ch0 < N_CH; ch0 += G) {
        const int nch = (N_CH - ch0 < G) ? (N_CH - ch0) : G;

        if (nch == 64) {
            // one block per (ch, t); both tensors in-block
            stft_mag_kernel<<<dim3(T_FRAMES * 64), dim3(256), 0, stream>>>(x0, x1, ws, ch0, nch, 1);
        } else {
            stft_mag_kernel<<<dim3(T_FRAMES, nch), dim3(256), 0, stream>>>(x0, x1, ws, ch0, nch, 0);
        }

        dim3 g2(N_CHUNKS, nch);
        ssim_kernel<<<g2, 256, 0, stream>>>(ws, out, ch0, nch);
    }
}

// Round 2
// 341.980 us; speedup vs baseline: 1.0777x; 1.0683x over previous
//
#include <hip/hip_runtime.h>
#include <math.h>

#ifndef M_PI
#define M_PI 3.14159265358979323846
#endif

constexpr int S_LEN    = 176400;
constexpr int NFFT     = 2048;
constexpr int NC       = 1024;
constexpr int HOP_     = 441;
constexpr int T_FRAMES = 401;
constexpr int F_BINS   = 1025;
constexpr int F_STRIDE = 1028;     // fp32 spec row stride (16B aligned)
constexpr int N_CH     = 64;
constexpr float EPS_   = 1e-8f;
constexpr float C1_    = 0.0004f;
constexpr float C2_    = 0.0036f;
constexpr float COV_NORM_ = 49.0f / 48.0f;

// workspace float offsets
constexpr int WIN_OFF  = 0;        // float[2048] hann window
constexpr int TWG_OFF  = 2048;     // float2[768]  tw[e] = exp(-2pi i e/1024)
constexpr int UTW_OFF  = 3584;     // float2[1025] exp(-i pi r/1024)
constexpr int SPEC_OFF = 5696;
constexpr int RPB_     = 10;
constexpr int N_CHUNKS = 40;

// LDS bank swizzle: phys(i) = i ^ ((i>>2)&15) ^ ((i>>6)&15).
// Triangular in GF(2) (bits0-3 ^= f(bits2-9)) -> bijective on [0,1024).
// Conflict-checked per pattern (16 consecutive lanes -> 16 distinct low-nibbles):
//  * pack b32 writes (ci consecutive)                         -> free
//  * in-place DIF stage reads/writes i0=4*tid-3q (+M,2M,3M),
//    M in {256,64,16,4,1}                                     -> free
//  * unpack digit-reversed reads ra=(rev4_8(tid)<<2)|k
//    (lane digits land in bits 6-9 -> folded back by >>6 term)-> free
//  * conjugate-partner reads rev10((1024-r)&1023)             -> <=2-way (free)
__device__ __forceinline__ int phys(int i) { return i ^ ((i >> 2) & 15) ^ ((i >> 6) & 15); }

__device__ __forceinline__ float2 cadd(float2 a, float2 b){ return make_float2(a.x+b.x, a.y+b.y); }
__device__ __forceinline__ float2 csub(float2 a, float2 b){ return make_float2(a.x-b.x, a.y-b.y); }
__device__ __forceinline__ float2 cmul(float2 a, float2 b){ return make_float2(a.x*b.x-a.y*b.y, a.x*b.y+a.y*b.x); }

__global__ __launch_bounds__(256) void init_tables_kernel(float* __restrict__ ws, float* __restrict__ out) {
    const int idx = blockIdx.x * 256 + threadIdx.x;
    if (idx < 64) out[idx] = 0.0f;
    if (idx < NFFT) {
        ws[WIN_OFF + idx] = 0.5f - 0.5f * cosf((float)(2.0 * M_PI / NFFT) * (float)idx);
    }
    if (idx < 768) {
        float ang = -2.0f * (float)M_PI * (float)idx / (float)NC;
        float s, c; sincosf(ang, &s, &c);
        ws[TWG_OFF + 2*idx] = c; ws[TWG_OFF + 2*idx+1] = s;
    }
    if (idx < F_BINS) {
        float ang = -(float)M_PI * (float)idx / (float)NC;
        float s, c; sincosf(ang, &s, &c);
        ws[UTW_OFF + 2*idx] = c; ws[UTW_OFF + 2*idx+1] = s;
    }
}

// In-place radix-4 DIF butterfly: reads 4 LDS slots, writes SAME 4 slots.
// Stage s (L = 1024/4^s): with a=x0+x2, b=x0-x2, c=x1+x3, d=x1-x3:
//   slot j      <- a + c
//   slot j+M    <- (b - i*d) * W_L^j
//   slot j+2M   <- (a - c)   * W_L^{2j}
//   slot j+3M   <- (b + i*d) * W_L^{3j}
// Output ends up base-4 digit-reversed (verified by N=16 hand-expansion).
__device__ __forceinline__ void r4_dif_inplace(
    float2* __restrict__ A, int r0, int r1, int r2, int r3,
    float2 w1, float2 w2, float2 w3, bool tw)
{
    float2 x0c = A[r0];
    float2 x1c = A[r1];
    float2 x2c = A[r2];
    float2 x3c = A[r3];

    float2 a = cadd(x0c, x2c);
    float2 b = csub(x0c, x2c);
    float2 c = cadd(x1c, x3c);
    float2 d = csub(x1c, x3c);

    float2 y0 = cadd(a, c);
    float2 y2 = csub(a, c);
    float2 y1 = make_float2(b.x + d.y, b.y - d.x);   // b - i*d
    float2 y3 = make_float2(b.x - d.y, b.y + d.x);   // b + i*d

    A[r0] = y0;
    A[r1] = tw ? cmul(y1, w1) : y1;
    A[r2] = tw ? cmul(y2, w2) : y2;
    A[r3] = tw ? cmul(y3, w3) : y3;
}

// Block-wide DUAL 1024-pt complex radix-4 IN-PLACE DIF: each block computes
// frame t of channel ch for BOTH tensors; the two FFTs share all addressing,
// reflect logic, window/twiddle fetches.  Single 16 KB LDS buffer (no ping-
// pong) -> 8 blocks/CU (thread-capped, 32 waves).  One barrier per stage
// (butterfly slot sets are disjoint across threads within a stage).
__global__ __launch_bounds__(256, 8) void stft_mag_kernel(
    const float* __restrict__ x0, const float* __restrict__ x1,
    float* __restrict__ ws, int ch0, int nch, int swizzle)
{
    __shared__ float2 buf[2 * NC];   // FFT0 at [0,NC), FFT1 at [NC,2NC)

    const int tid = threadIdx.x;

    int ch, t;
    if (swizzle) {
        int g = blockIdx.x;
        ch = ch0 + (g & 7) * 8 + ((g >> 3) & 7);
        t  = g >> 6;
    } else {
        t  = blockIdx.x;
        ch = ch0 + blockIdx.y;
    }

    const float* __restrict__ xin0 = x0 + (size_t)ch * S_LEN;
    const float* __restrict__ xin1 = x1 + (size_t)ch * S_LEN;
    const float*  __restrict__ win = ws + WIN_OFF;
    const float2* __restrict__ twg = (const float2*)(ws + TWG_OFF);
    const float2* __restrict__ utw = (const float2*)(ws + UTW_OFF);

    // ---- pack: flat float index n over [0,2048); complex ci = n>>1 (swizzled)
    const int base = t * HOP_ - NFFT / 2;
    float* fA0 = (float*)buf;             // FFT0
    float* fA1 = (float*)(buf + NC);      // FFT1 (+8 KB)
    if (base >= 0 && base + NFFT <= S_LEN) {
        // interior frame (395 of 401): no reflect math
        #pragma unroll
        for (int k = 0; k < NFFT / 256; ++k) {
            int n = k * 256 + tid;
            int j = base + n;
            float w = win[n];
            int p = 2 * phys(n >> 1) + (n & 1);
            fA0[p] = xin0[j] * w;
            fA1[p] = xin1[j] * w;
        }
    } else {
        #pragma unroll
        for (int k = 0; k < NFFT / 256; ++k) {
            int n = k * 256 + tid;
            int j = base + n;
            j = (j < 0) ? -j : j;
            j = (j >= S_LEN) ? (2 * S_LEN - 2 - j) : j;
            float w = win[n];
            int p = 2 * phys(n >> 1) + (n & 1);
            fA0[p] = xin0[j] * w;
            fA1[p] = xin1[j] * w;
        }
    }
    __syncthreads();

    // ---- 5-stage in-place radix-4 DIF, x2 FFTs.  Stage s: M = 256>>2s,
    // q = tid & (M-1), i0 = 4*(tid-q)+q, twiddle exponent e = q*4^s
    // (W_L^{q} = tw[q * 1024/L], L = 1024/4^s; max 3e = 765 < 768).
    #pragma unroll
    for (int s = 0; s < 5; ++s) {
        const int M  = 256 >> (2 * s);
        const int q  = tid & (M - 1);
        const int e  = q << (2 * s);
        const int i0 = 4 * (tid - q) + q;

        const int r0 = phys(i0);
        const int r1 = phys(i0 + M);
        const int r2 = phys(i0 + 2 * M);
        const int r3 = phys(i0 + 3 * M);

        float2 w1, w2, w3;
        if (s < 4) {                       // s==4: all twiddles are 1
            w1 = twg[e];
            w2 = twg[2 * e];
            w3 = twg[3 * e];
        } else {
            w1 = w2 = w3 = make_float2(1.0f, 0.0f);
        }

        r4_dif_inplace(buf,      r0, r1, r2, r3, w1, w2, w3, s < 4);
        r4_dif_inplace(buf + NC, r0, r1, r2, r3, w1, w2, w3, s < 4);

        __syncthreads();
    }

    // ---- real-FFT unpack + magnitude + fp32 coalesced stores (both tensors)
    // Data is base-4 digit-reversed: Z[k] lives at slot rev4(k).
    // r = k*256+tid -> rev4(r) = (rev4_8(tid)<<2) | k   (1 op/iter).
    const size_t perT = (size_t)T_FRAMES * F_STRIDE;
    float* __restrict__ sout0 =
        ws + SPEC_OFF + (size_t)(ch - ch0) * perT + (size_t)t * F_STRIDE;
    float* __restrict__ sout1 = sout0 + (size_t)nch * perT;

    const int R8 = ((tid & 3) << 6) | ((tid & 12) << 2) | ((tid >> 2) & 12) | ((tid >> 6) & 3);

    #pragma unroll
    for (int k = 0; k < 5; ++k) {
        int r = k * 256 + tid;
        if (k < 4 || tid == 0) {
            const int ra = (k < 4) ? ((R8 << 2) | k) : 0;          // rev4(r & 1023)
            const int rn = (NC - r) & (NC - 1);
            const int rb = ((rn & 3) << 8) | ((rn & 12) << 4) | (rn & 48)
                         | ((rn >> 4) & 12) | ((rn >> 8) & 3);     // rev4(rn)
            const int ia = phys(ra);
            const int ib = phys(rb);
            float2 wu = utw[r];

            {   // tensor 0
                float2 Zr = buf[ia];
                float2 Zn = buf[ib];
                float Ex = 0.5f * (Zr.x + Zn.x);
                float Ey = 0.5f * (Zr.y - Zn.y);
                float Ox = 0.5f * (Zr.y + Zn.y);
                float Oy = 0.5f * (Zn.x - Zr.x);
                float Xx = Ex + wu.x * Ox - wu.y * Oy;
                float Xy = Ey + wu.x * Oy + wu.y * Ox;
                sout0[r] = sqrtf(fmaxf(Xx * Xx + Xy * Xy, EPS_));
            }
            {   // tensor 1
                float2 Zr = buf[NC + ia];
                float2 Zn = buf[NC + ib];
                float Ex = 0.5f * (Zr.x + Zn.x);
                float Ey = 0.5f * (Zr.y - Zn.y);
                float Ox = 0.5f * (Zr.y + Zn.y);
                float Oy = 0.5f * (Zn.x - Zr.x);
                float Xx = Ex + wu.x * Ox - wu.y * Oy;
                float Xy = Ey + wu.x * Oy + wu.y * Ox;
                sout1[r] = sqrtf(fmaxf(Xx * Xx + Xy * Xy, EPS_));
            }
        }
    }
}

// SSIM (proven R5/R7): thread owns 4 cols; float4 global loads; rolling vertical
// sums; 5 scalar LDS arrays with lane stride 5 -> conflict-free.
__global__ __launch_bounds__(256) void ssim_kernel(
    const float* __restrict__ ws, float* __restrict__ out,
    int ch0, int nch)
{
    __shared__ float csx[1284], csy[1284], csxx[1284], csyy[1284], csxy[1284];
    __shared__ double red[256];

    const int tid = threadIdx.x;
    const int cg  = blockIdx.y;
    const int ch  = ch0 + cg;
    const float* __restrict__ spec = ws + SPEC_OFF;
    const size_t per_ch = (size_t)T_FRAMES * F_STRIDE;
    const float* __restrict__ X = spec + (size_t)cg * per_ch;
    const float* __restrict__ Y = spec + ((size_t)nch + cg) * per_ch;

    const int t_begin = 3 + blockIdx.x * RPB_;
    const int t_end_  = min(t_begin + RPB_, T_FRAMES - 3);

    const int fv = tid << 2;
    const bool last = (tid == 255);
    const float inv49 = 1.0f / 49.0f;
    double acc = 0.0;

    float sx[4] = {0,0,0,0}, sy[4] = {0,0,0,0}, sxx[4] = {0,0,0,0},
          syy[4] = {0,0,0,0}, sxy[4] = {0,0,0,0};
    float s5[5] = {0,0,0,0,0};

    for (int rr = t_begin - 3; rr < t_begin + 3; ++rr) {
        float4 xv = *(const float4*)(X + (size_t)rr * F_STRIDE + fv);
        float4 yv = *(const float4*)(Y + (size_t)rr * F_STRIDE + fv);
        float xa[4] = {xv.x, xv.y, xv.z, xv.w}, ya[4] = {yv.x, yv.y, yv.z, yv.w};
        #pragma unroll
        for (int c = 0; c < 4; ++c) {
            sx[c] += xa[c]; sy[c] += ya[c];
            sxx[c] += xa[c]*xa[c]; syy[c] += ya[c]*ya[c]; sxy[c] += xa[c]*ya[c];
        }
        if (last) {
            float xe = X[(size_t)rr * F_STRIDE + 1024];
            float ye = Y[(size_t)rr * F_STRIDE + 1024];
            s5[0] += xe; s5[1] += ye; s5[2] += xe*xe; s5[3] += ye*ye; s5[4] += xe*ye;
        }
    }

    float4 ax, ay, bx, by; float a5x=0, a5y=0, b5x=0, b5y=0;
    ax = *(const float4*)(X + (size_t)(t_begin + 3) * F_STRIDE + fv);
    ay = *(const float4*)(Y + (size_t)(t_begin + 3) * F_STRIDE + fv);
    bx = *(const float4*)(X + (size_t)(t_begin - 3) * F_STRIDE + fv);
    by = *(const float4*)(Y + (size_t)(t_begin - 3) * F_STRIDE + fv);
    if (last) {
        a5x = X[(size_t)(t_begin + 3) * F_STRIDE + 1024];
        a5y = Y[(size_t)(t_begin + 3) * F_STRIDE + 1024];
        b5x = X[(size_t)(t_begin - 3) * F_STRIDE + 1024];
        b5y = Y[(size_t)(t_begin - 3) * F_STRIDE + 1024];
    }

    const int fo = 3 + (tid << 2);

    for (int t = t_begin; t < t_end_; ++t) {
        {
            float xa[4] = {ax.x, ax.y, ax.z, ax.w}, ya[4] = {ay.x, ay.y, ay.z, ay.w};
            #pragma unroll
            for (int c = 0; c < 4; ++c) {
                sx[c] += xa[c]; sy[c] += ya[c];
                sxx[c] += xa[c]*xa[c]; syy[c] += ya[c]*ya[c]; sxy[c] += xa[c]*ya[c];
                int p = 5 * tid + c;
                csx[p] = sx[c]; csy[p] = sy[c];
                csxx[p] = sxx[c]; csyy[p] = syy[c]; csxy[p] = sxy[c];
            }
            if (last) {
                s5[0] += a5x; s5[1] += a5y; s5[2] += a5x*a5x; s5[3] += a5y*a5y; s5[4] += a5x*a5y;
                csx[1280] = s5[0]; csy[1280] = s5[1];
                csxx[1280] = s5[2]; csyy[1280] = s5[3]; csxy[1280] = s5[4];
            }
        }
        __syncthreads();

        {
            float xa[4] = {bx.x, bx.y, bx.z, bx.w}, ya[4] = {by.x, by.y, by.z, by.w};
            #pragma unroll
            for (int c = 0; c < 4; ++c) {
                sx[c] -= xa[c]; sy[c] -= ya[c];
                sxx[c] -= xa[c]*xa[c]; syy[c] -= ya[c]*ya[c]; sxy[c] -= xa[c]*ya[c];
            }
            if (last) {
                s5[0] -= b5x; s5[1] -= b5y; s5[2] -= b5x*b5x; s5[3] -= b5y*b5y; s5[4] -= b5x*b5y;
            }
        }
        if (t + 1 < t_end_) {
            ax = *(const float4*)(X + (size_t)(t + 4) * F_STRIDE + fv);
            ay = *(const float4*)(Y + (size_t)(t + 4) * F_STRIDE + fv);
            bx = *(const float4*)(X + (size_t)(t - 2) * F_STRIDE + fv);
            by = *(const float4*)(Y + (size_t)(t - 2) * F_STRIDE + fv);
            if (last) {
                a5x = X[(size_t)(t + 4) * F_STRIDE + 1024];
                a5y = Y[(size_t)(t + 4) * F_STRIDE + 1024];
                b5x = X[(size_t)(t - 2) * F_STRIDE + 1024];
                b5y = Y[(size_t)(t - 2) * F_STRIDE + 1024];
            }
        }

        if (tid < 255) {
            float tx[10], ty[10], txx[10], tyy[10], txy[10];
            #pragma unroll
            for (int d = 0; d < 10; ++d) {
                int p = 5 * tid + d + (d >> 2);
                tx[d] = csx[p]; ty[d] = csy[p];
                txx[d] = csxx[p]; tyy[d] = csyy[p]; txy[d] = csxy[p];
            }
            float wx  = tx[0]+tx[1]+tx[2]+tx[3]+tx[4]+tx[5]+tx[6];
            float wy  = ty[0]+ty[1]+ty[2]+ty[3]+ty[4]+ty[5]+ty[6];
            float wxx = txx[0]+txx[1]+txx[2]+txx[3]+txx[4]+txx[5]+txx[6];
            float wyy = tyy[0]+tyy[1]+tyy[2]+tyy[3]+tyy[4]+tyy[5]+tyy[6];
            float wxy = txy[0]+txy[1]+txy[2]+txy[3]+txy[4]+txy[5]+txy[6];
            #pragma unroll
            for (int c = 0; c < 4; ++c) {
                if (fo + c <= 1021) {
                    float ux  = wx * inv49, uy  = wy * inv49;
                    float uxx = wxx * inv49, uyy = wyy * inv49, uxy = wxy * inv49;
                    float vx  = COV_NORM_ * (uxx - ux * ux);
                    float vy  = COV_NORM_ * (uyy - uy * uy);
                    float vxy = COV_NORM_ * (uxy - ux * uy);
                    float Sv = ((2.f * ux * uy + C1_) * (2.f * vxy + C2_)) /
                               ((ux * ux + uy * uy + C1_) * (vx + vy + C2_));
                    acc += (double)Sv;
                }
                if (c < 3) {
                    wx  += tx[c+7]  - tx[c];
                    wy  += ty[c+7]  - ty[c];
                    wxx += txx[c+7] - txx[c];
                    wyy += tyy[c+7] - tyy[c];
                    wxy += txy[c+7] - txy[c];
                }
            }
        }
        __syncthreads();
    }

    red[tid] = acc;
    __syncthreads();
    for (int off = 128; off > 0; off >>= 1) {
        if (tid < off) red[tid] += red[tid + off];
        __syncthreads();
    }
    if (tid == 0) {
        atomicAdd(&out[ch], (float)(red[0] / (395.0 * 1019.0)));
    }
}

extern "C" void kernel_launch(void* const* d_in, const int* in_sizes, int n_in,
                              void* d_out, int out_size, void* d_ws, size_t ws_size,
                              hipStream_t stream) {
    const float* x0 = (const float*)d_in[0];   // output
    const float* x1 = (const float*)d_in[1];   // target
    float* out = (float*)d_out;
    float* ws  = (float*)d_ws;

    const size_t table_bytes  = (size_t)SPEC_OFF * sizeof(float);
    const size_t per_ch_bytes = (size_t)2 * T_FRAMES * F_STRIDE * sizeof(float);
    int G = (int)((ws_size - table_bytes) / per_ch_bytes);
    if (G > N_CH) G = N_CH;
    if (G < 1)    G = 1;

    init_tables_kernel<<<dim3(16), dim3(256), 0, stream>>>(ws, out);

    for (int ch0 = 0; ch0 < N_CH; ch0 += G) {
        const int nch = (N_CH - ch0 < G) ? (N_CH - ch0) : G;

        if (nch == 64) {
            // one block per (ch, t); both tensors in-block
            stft_mag_kernel<<<dim3(T_FRAMES * 64), dim3(256), 0, stream>>>(x0, x1, ws, ch0, nch, 1);
        } else {
            stft_mag_kernel<<<dim3(T_FRAMES, nch), dim3(256), 0, stream>>>(x0, x1, ws, ch0, nch, 0);
        }

        dim3 g2(N_CHUNKS, nch);
        ssim_kernel<<<g2, 256, 0, stream>>>(ws, out, ch0, nch);
    }
}